// Round 8
// baseline (2786.366 us; speedup 1.0000x reference)
//
#include <hip/hip_runtime.h>
#include <hip/hip_bf16.h>
#include <math.h>
#include <stdint.h>

#define TOK 32768
#define DIM 1024
#define NE 8

typedef __attribute__((ext_vector_type(8))) short bf16x8;
typedef __attribute__((ext_vector_type(4))) float f32x4;
typedef unsigned short ushort_t;

__device__ __forceinline__ unsigned short f2b(float x) {
  union { float f; unsigned u; } v; v.f = x;
  unsigned r = v.u + 0x7fffu + ((v.u >> 16) & 1u);
  return (unsigned short)(r >> 16);
}

__device__ __forceinline__ void async16(void* lds, const void* g) {
  auto* lp = (__attribute__((address_space(3))) uint32_t*)lds;
  auto* gp = (__attribute__((address_space(1))) uint32_t*)(const_cast<void*>(g));
  __builtin_amdgcn_global_load_lds(gp, lp, 16, 0, 0);
}

// ---- router: STRICTLY SEQUENTIAL f32 FMA scores (mimic BLAS k-loop), ------
// ---- f32 softmax, top2 on f32 probs, first-index tie-break ----------------
__global__ __launch_bounds__(256) void router_seq(
    const float* __restrict__ tokens, const float* __restrict__ rw,
    int* __restrict__ topi, float* __restrict__ topv) {
  const int tid = threadIdx.x;
  const int e = tid & 7;
  const int tr = tid >> 3; /* 0..31 */
  const int t = blockIdx.x * 32 + tr;
  const float* x = tokens + (size_t)t * DIM;
  const float* w = rw + (size_t)e * DIM;
  float s = 0.f;
  for (int k = 0; k < DIM; k++) s = fmaf(x[k], w[k], s);
  __shared__ float sc[256];
  sc[tid] = s;
  __syncthreads();
  if (e == 0) {
    float p[NE];
    float m = sc[tr * 8];
#pragma unroll
    for (int i = 1; i < NE; i++) m = fmaxf(m, sc[tr * 8 + i]);
    float sum = 0.f;
#pragma unroll
    for (int i = 0; i < NE; i++) {
      p[i] = expf(sc[tr * 8 + i] - m);
      sum += p[i];
    }
#pragma unroll
    for (int i = 0; i < NE; i++) p[i] = p[i] / sum;
    int e0 = 0;
#pragma unroll
    for (int i = 1; i < NE; i++) if (p[i] > p[e0]) e0 = i;
    int e1 = (e0 == 0) ? 1 : 0;
#pragma unroll
    for (int i = 0; i < NE; i++) if (i != e0 && p[i] > p[e1]) e1 = i;
    topi[t * 2] = e0;     topv[t * 2] = p[e0];
    topi[t * 2 + 1] = e1; topv[t * 2 + 1] = p[e1];
  }
}

// ---------------- dense gate matrix [T][E] ----------------------------------
__global__ __launch_bounds__(256) void gate_kernel(
    const int* __restrict__ topi, const float* __restrict__ topv,
    float* __restrict__ gate) {
  const int t = blockIdx.x * 256 + threadIdx.x;
  if (t >= TOK) return;
  const int i0 = topi[t * 2], i1 = topi[t * 2 + 1];
  const float v0 = topv[t * 2], v1 = topv[t * 2 + 1];
#pragma unroll
  for (int e = 0; e < NE; e++)
    gate[(size_t)t * NE + e] = (e == i0 ? v0 : 0.f) + (e == i1 ? v1 : 0.f);
}

// ---------------- weights: [E][K][N] f32 -> [E][N][K] bf16 (B^T layout) -----
__global__ __launch_bounds__(256) void transpose_cast(
    const float* __restrict__ w, ushort_t* __restrict__ wT) {
  __shared__ float tile[64][65];
  const int e = blockIdx.z;
  const int n0 = blockIdx.x * 64, k0 = blockIdx.y * 64;
  const int tx = threadIdx.x & 63, ty = threadIdx.x >> 6;
  const float* src = w + ((size_t)e << 20);
  ushort_t* dst = wT + ((size_t)e << 20);
#pragma unroll
  for (int r = ty; r < 64; r += 4)
    tile[r][tx] = src[(size_t)(k0 + r) * DIM + n0 + tx];
  __syncthreads();
#pragma unroll
  for (int r = ty; r < 64; r += 4)
    dst[(size_t)(n0 + r) * DIM + k0 + tx] = f2b(tile[tx][r]);
}

// ---------------- DENSE per-expert GEMM, 128x128 tile, BK=32, 4 waves -------
// PASS 0: H[r,:]   = gelu( bf16(tokens[r,:]) @ B^T )          (bf16 out)
// PASS 1: out[r,:] += gate[r][e] * ( H[r,:] @ B^T )           (exclusive +=)
template <int PASS>
__global__ __launch_bounds__(256) void dgemm(
    const float* __restrict__ tokens, const ushort_t* __restrict__ Hin,
    const ushort_t* __restrict__ B, const float* __restrict__ gate, int e,
    ushort_t* __restrict__ Hout, float* __restrict__ out) {
  const int m0 = blockIdx.x * 128;
  const int n0 = blockIdx.y * 128;
  __shared__ ushort_t As[128 * 32];
  __shared__ ushort_t Bs[128 * 32];
  const int tid = threadIdx.x;
  const int lane = tid & 63;
  const int wave = tid >> 6;
  const int wm = wave >> 1, wn = wave & 1;
  const int lr = lane & 15;
  const int lk = (lane >> 4) << 3;

  const float* ga = nullptr;
  const ushort_t* asrc0 = nullptr;
  const ushort_t* asrc1 = nullptr;
  if (PASS == 0) {
    ga = tokens + (size_t)(m0 + (tid >> 1)) * DIM + ((tid & 1) << 4);
  } else {
    asrc0 = Hin + (size_t)(m0 + (tid >> 2)) * DIM + ((tid & 3) << 3);
    asrc1 = Hin + (size_t)(m0 + 64 + (tid >> 2)) * DIM + ((tid & 3) << 3);
  }
  const ushort_t* bsrc0 = B + (size_t)(n0 + (tid >> 2)) * DIM + ((tid & 3) << 3);
  const ushort_t* bsrc1 =
      B + (size_t)(n0 + 64 + (tid >> 2)) * DIM + ((tid & 3) << 3);
  ushort_t* lA0 = &As[(tid & ~63) * 8];
  ushort_t* lA1 = &As[(256 + (tid & ~63)) * 8];
  ushort_t* lB0 = &Bs[(tid & ~63) * 8];
  ushort_t* lB1 = &Bs[(256 + (tid & ~63)) * 8];

  f32x4 acc[4][4] = {};

  for (int k0 = 0; k0 < DIM; k0 += 32) {
    if (PASS == 0) {
      const float4 f0 = *(const float4*)(ga + k0);
      const float4 f1 = *(const float4*)(ga + k0 + 4);
      const float4 f2 = *(const float4*)(ga + k0 + 8);
      const float4 f3 = *(const float4*)(ga + k0 + 12);
      bf16x8 h0, h1;
      h0[0] = (short)f2b(f0.x); h0[1] = (short)f2b(f0.y);
      h0[2] = (short)f2b(f0.z); h0[3] = (short)f2b(f0.w);
      h0[4] = (short)f2b(f1.x); h0[5] = (short)f2b(f1.y);
      h0[6] = (short)f2b(f1.z); h0[7] = (short)f2b(f1.w);
      h1[0] = (short)f2b(f2.x); h1[1] = (short)f2b(f2.y);
      h1[2] = (short)f2b(f2.z); h1[3] = (short)f2b(f2.w);
      h1[4] = (short)f2b(f3.x); h1[5] = (short)f2b(f3.y);
      h1[6] = (short)f2b(f3.z); h1[7] = (short)f2b(f3.w);
      *(bf16x8*)&As[tid * 16] = h0;
      *(bf16x8*)&As[tid * 16 + 8] = h1;
    } else {
      async16(lA0, asrc0 + k0);
      async16(lA1, asrc1 + k0);
    }
    async16(lB0, bsrc0 + k0);
    async16(lB1, bsrc1 + k0);
    __syncthreads();
    bf16x8 a[4], b[4];
#pragma unroll
    for (int i = 0; i < 4; i++)
      a[i] = *(const bf16x8*)&As[(wm * 64 + i * 16 + lr) * 32 + lk];
#pragma unroll
    for (int i = 0; i < 4; i++)
      b[i] = *(const bf16x8*)&Bs[(wn * 64 + i * 16 + lr) * 32 + lk];
#pragma unroll
    for (int mi = 0; mi < 4; mi++)
#pragma unroll
      for (int ni = 0; ni < 4; ni++)
        acc[mi][ni] = __builtin_amdgcn_mfma_f32_16x16x32_bf16(
            a[mi], b[ni], acc[mi][ni], 0, 0, 0);
    __syncthreads();
  }

  const int grow = (lane >> 4) << 2;
  if (PASS == 0) {
#pragma unroll
    for (int mi = 0; mi < 4; mi++) {
      const int rbase = m0 + wm * 64 + mi * 16 + grow;
#pragma unroll
      for (int ni = 0; ni < 4; ni++) {
        const int col = n0 + wn * 64 + ni * 16 + lr;
#pragma unroll
        for (int r = 0; r < 4; r++) {
          const float x = acc[mi][ni][r];
          const float g = 0.5f * x * (1.f + erff(x * 0.70710678118654752f));
          Hout[(size_t)(rbase + r) * DIM + col] = f2b(g);
        }
      }
    }
  } else {
#pragma unroll
    for (int mi = 0; mi < 4; mi++) {
      const int rbase = m0 + wm * 64 + mi * 16 + grow;
#pragma unroll
      for (int r = 0; r < 4; r++) {
        const int rr = rbase + r;
        const float gv = gate[(size_t)rr * NE + e];
        float* op = out + (size_t)rr * DIM + n0 + wn * 64 + lr;
#pragma unroll
        for (int ni = 0; ni < 4; ni++)
          op[ni * 16] += gv * acc[mi][ni][r];
      }
    }
  }
}

extern "C" void kernel_launch(void* const* d_in, const int* in_sizes, int n_in,
                              void* d_out, int out_size, void* d_ws,
                              size_t ws_size, hipStream_t stream) {
  (void)in_sizes; (void)n_in; (void)ws_size;
  const float* tokens = (const float*)d_in[0];
  const float* rw = (const float*)d_in[1];
  const float* w1 = (const float*)d_in[2];
  const float* w2 = (const float*)d_in[3];
  float* out = (float*)d_out;

  char* ws = (char*)d_ws;
  size_t off = 0;
  auto alloc = [&](size_t b) {
    size_t o = off;
    off += (b + 255) & ~(size_t)255;
    return o;
  };
  int* topi = (int*)(ws + alloc((size_t)TOK * 2 * 4));
  float* topv = (float*)(ws + alloc((size_t)TOK * 2 * 4));
  float* gate = (float*)(ws + alloc((size_t)TOK * NE * 4));
  ushort_t* w1T = (ushort_t*)(ws + alloc((size_t)NE * DIM * DIM * 2));
  ushort_t* w2T = (ushort_t*)(ws + alloc((size_t)NE * DIM * DIM * 2));
  ushort_t* H = (ushort_t*)(ws + alloc((size_t)TOK * DIM * 2));

  router_seq<<<TOK / 32, 256, 0, stream>>>(tokens, rw, topi, topv);
  gate_kernel<<<TOK / 256, 256, 0, stream>>>(topi, topv, gate);
  dim3 tg(16, 16, 8);
  transpose_cast<<<tg, 256, 0, stream>>>(w1, w1T);
  transpose_cast<<<tg, 256, 0, stream>>>(w2, w2T);
  hipMemsetAsync(out, 0, (size_t)out_size * 4, stream);
  dim3 dg(TOK / 128, 8);
  for (int e = 0; e < NE; e++) {
    dgemm<0><<<dg, 256, 0, stream>>>(tokens, H, w1T + ((size_t)e << 20), gate,
                                     e, H, out);
    dgemm<1><<<dg, 256, 0, stream>>>(tokens, H, w2T + ((size_t)e << 20), gate,
                                     e, H, out);
  }
}

// Round 9
// 1507.879 us; speedup vs baseline: 1.8479x; 1.8479x over previous
//
#include <hip/hip_runtime.h>
#include <hip/hip_bf16.h>
#include <math.h>
#include <stdint.h>

#define TOK 32768
#define DIM 1024
#define NE 8
#define BMCAP (2 * TOK + NE * 128) /* 66560 row slots (segments padded to 128) */
#define CH 32768                   /* H chunk rows */
#define NCHUNK ((BMCAP + CH - 1) / CH) /* 3 */

typedef __attribute__((ext_vector_type(8))) short bf16x8;
typedef __attribute__((ext_vector_type(4))) float f32x4;
typedef unsigned short ushort_t;

__device__ __forceinline__ unsigned short f2b(float x) {
  union { float f; unsigned u; } v; v.f = x;
  unsigned r = v.u + 0x7fffu + ((v.u >> 16) & 1u);
  return (unsigned short)(r >> 16);
}

__device__ __forceinline__ void async16(void* lds, const void* g) {
  auto* lp = (__attribute__((address_space(3))) uint32_t*)lds;
  auto* gp = (__attribute__((address_space(1))) uint32_t*)(const_cast<void*>(g));
  __builtin_amdgcn_global_load_lds(gp, lp, 16, 0, 0);
}

// ---- router: STRICTLY SEQUENTIAL f32 FMA scores (matches np top-k) ---------
// FROZEN: this exact accumulation order is what makes top-2 agree with ref.
__global__ __launch_bounds__(256) void router_seq(
    const float* __restrict__ tokens, const float* __restrict__ rw,
    int* __restrict__ topi, float* __restrict__ topv, int* __restrict__ cnt) {
  const int tid = threadIdx.x;
  const int e = tid & 7;
  const int tr = tid >> 3; /* 0..31 */
  const int t = blockIdx.x * 32 + tr;
  const float* x = tokens + (size_t)t * DIM;
  const float* w = rw + (size_t)e * DIM;
  float s = 0.f;
  for (int k = 0; k < DIM; k++) s = fmaf(x[k], w[k], s);
  __shared__ float sc[256];
  sc[tid] = s;
  __syncthreads();
  if (e == 0) {
    float p[NE];
    float m = sc[tr * 8];
#pragma unroll
    for (int i = 1; i < NE; i++) m = fmaxf(m, sc[tr * 8 + i]);
    float sum = 0.f;
#pragma unroll
    for (int i = 0; i < NE; i++) {
      p[i] = expf(sc[tr * 8 + i] - m);
      sum += p[i];
    }
#pragma unroll
    for (int i = 0; i < NE; i++) p[i] = p[i] / sum;
    int e0 = 0;
#pragma unroll
    for (int i = 1; i < NE; i++) if (p[i] > p[e0]) e0 = i;
    int e1 = (e0 == 0) ? 1 : 0;
#pragma unroll
    for (int i = 0; i < NE; i++) if (i != e0 && p[i] > p[e1]) e1 = i;
    topi[t * 2] = e0;     topv[t * 2] = p[e0];
    topi[t * 2 + 1] = e1; topv[t * 2 + 1] = p[e1];
    atomicAdd(&cnt[e0], 1);
    atomicAdd(&cnt[e1], 1);
  }
}

// ---------------- weights: [E][K][N] f32 -> [E][N][K] bf16 (B^T layout) -----
__global__ __launch_bounds__(256) void transpose_cast(
    const float* __restrict__ w, ushort_t* __restrict__ wT) {
  __shared__ float tile[64][65];
  const int e = blockIdx.z;
  const int n0 = blockIdx.x * 64, k0 = blockIdx.y * 64;
  const int tx = threadIdx.x & 63, ty = threadIdx.x >> 6;
  const float* src = w + ((size_t)e << 20);
  ushort_t* dst = wT + ((size_t)e << 20);
#pragma unroll
  for (int r = ty; r < 64; r += 4)
    tile[r][tx] = src[(size_t)(k0 + r) * DIM + n0 + tx];
  __syncthreads();
#pragma unroll
  for (int r = ty; r < 64; r += 4)
    dst[(size_t)(n0 + r) * DIM + k0 + tx] = f2b(tile[tx][r]);
}

// ---------------- ctrl: [0..7] count, [8..15] cursor, [16..24] seg_start ----
__global__ void prefix_kernel(int* ctrl) {
  if (threadIdx.x == 0 && blockIdx.x == 0) {
    int s = 0;
    for (int e = 0; e < NE; e++) {
      ctrl[16 + e] = s;
      ctrl[8 + e] = s;
      s += (ctrl[e] + 127) & ~127;
    }
    ctrl[24] = s; /* Mpad */
  }
}

__global__ __launch_bounds__(256) void init_rows(
    int* __restrict__ row_token, float* __restrict__ row_gate) {
  const int i = blockIdx.x * 256 + threadIdx.x;
  if (i < BMCAP) { row_token[i] = TOK; row_gate[i] = 0.f; }
}

__global__ __launch_bounds__(256) void assign_kernel(
    const int* __restrict__ topi, const float* __restrict__ topv,
    int* __restrict__ ctrl, int* __restrict__ row_token,
    float* __restrict__ row_gate) {
  const int t = blockIdx.x * 256 + threadIdx.x;
  if (t >= TOK) return;
#pragma unroll
  for (int k = 0; k < 2; k++) {
    const int e = topi[t * 2 + k];
    const int pos = atomicAdd(&ctrl[8 + e], 1);
    row_token[pos] = t;
    row_gate[pos] = topv[t * 2 + k];
  }
}

// ------- grouped GEMM, 128x128 tile, BK=32, 4 waves, H chunked --------------
// PASS 0: H[r-cbase,:] = gelu( bf16(tokens[row_token[r],:]) @ wT[e]^T )
// PASS 1: out[row_token[r],:] += row_gate[r] * ( H[r-cbase,:] @ wT[e]^T )
template <int PASS>
__global__ __launch_bounds__(256) void dgemm(
    const float* __restrict__ tokens, const ushort_t* __restrict__ Hin,
    const ushort_t* __restrict__ Wt, const int* __restrict__ row_token,
    const float* __restrict__ row_gate, const int* __restrict__ ctrl,
    int cbase, ushort_t* __restrict__ Hout, float* __restrict__ out) {
  const int Mpad = ctrl[24];
  const int m0 = cbase + blockIdx.x * 128;
  if (m0 >= Mpad) return;
  const int m0loc = m0 - cbase;
  const int n0 = blockIdx.y * 128;
  int e = 0;
#pragma unroll
  for (int i = 0; i < NE - 1; i++)
    if (m0 >= ctrl[16 + i + 1]) e = i + 1;
  const ushort_t* B = Wt + ((size_t)e << 20);

  __shared__ ushort_t As[128 * 32];
  __shared__ ushort_t Bs[128 * 32];
  const int tid = threadIdx.x;
  const int lane = tid & 63;
  const int wave = tid >> 6;
  const int wm = wave >> 1, wn = wave & 1;
  const int lr = lane & 15;
  const int lk = (lane >> 4) << 3;

  const float* ga = nullptr;
  const ushort_t* asrc0 = nullptr;
  const ushort_t* asrc1 = nullptr;
  if (PASS == 0) {
    int tk = row_token[m0 + (tid >> 1)];
    if (tk >= TOK) tk = 0; /* pad rows: any valid row, result unused */
    ga = tokens + (size_t)tk * DIM + ((tid & 1) << 4);
  } else {
    asrc0 = Hin + (size_t)(m0loc + (tid >> 2)) * DIM + ((tid & 3) << 3);
    asrc1 = Hin + (size_t)(m0loc + 64 + (tid >> 2)) * DIM + ((tid & 3) << 3);
  }
  const ushort_t* bsrc0 = B + (size_t)(n0 + (tid >> 2)) * DIM + ((tid & 3) << 3);
  const ushort_t* bsrc1 =
      B + (size_t)(n0 + 64 + (tid >> 2)) * DIM + ((tid & 3) << 3);
  ushort_t* lA0 = &As[(tid & ~63) * 8];
  ushort_t* lA1 = &As[(256 + (tid & ~63)) * 8];
  ushort_t* lB0 = &Bs[(tid & ~63) * 8];
  ushort_t* lB1 = &Bs[(256 + (tid & ~63)) * 8];

  f32x4 acc[4][4] = {};

  for (int k0 = 0; k0 < DIM; k0 += 32) {
    if (PASS == 0) {
      const float4 f0 = *(const float4*)(ga + k0);
      const float4 f1 = *(const float4*)(ga + k0 + 4);
      const float4 f2 = *(const float4*)(ga + k0 + 8);
      const float4 f3 = *(const float4*)(ga + k0 + 12);
      bf16x8 h0, h1;
      h0[0] = (short)f2b(f0.x); h0[1] = (short)f2b(f0.y);
      h0[2] = (short)f2b(f0.z); h0[3] = (short)f2b(f0.w);
      h0[4] = (short)f2b(f1.x); h0[5] = (short)f2b(f1.y);
      h0[6] = (short)f2b(f1.z); h0[7] = (short)f2b(f1.w);
      h1[0] = (short)f2b(f2.x); h1[1] = (short)f2b(f2.y);
      h1[2] = (short)f2b(f2.z); h1[3] = (short)f2b(f2.w);
      h1[4] = (short)f2b(f3.x); h1[5] = (short)f2b(f3.y);
      h1[6] = (short)f2b(f3.z); h1[7] = (short)f2b(f3.w);
      *(bf16x8*)&As[tid * 16] = h0;
      *(bf16x8*)&As[tid * 16 + 8] = h1;
    } else {
      async16(lA0, asrc0 + k0);
      async16(lA1, asrc1 + k0);
    }
    async16(lB0, bsrc0 + k0);
    async16(lB1, bsrc1 + k0);
    __syncthreads();
    bf16x8 a[4], b[4];
#pragma unroll
    for (int i = 0; i < 4; i++)
      a[i] = *(const bf16x8*)&As[(wm * 64 + i * 16 + lr) * 32 + lk];
#pragma unroll
    for (int i = 0; i < 4; i++)
      b[i] = *(const bf16x8*)&Bs[(wn * 64 + i * 16 + lr) * 32 + lk];
#pragma unroll
    for (int mi = 0; mi < 4; mi++)
#pragma unroll
      for (int ni = 0; ni < 4; ni++)
        acc[mi][ni] = __builtin_amdgcn_mfma_f32_16x16x32_bf16(
            a[mi], b[ni], acc[mi][ni], 0, 0, 0);
    __syncthreads();
  }

  const int grow = (lane >> 4) << 2;
  if (PASS == 0) {
#pragma unroll
    for (int mi = 0; mi < 4; mi++) {
      const int rloc = m0loc + wm * 64 + mi * 16 + grow;
#pragma unroll
      for (int ni = 0; ni < 4; ni++) {
        const int col = n0 + wn * 64 + ni * 16 + lr;
#pragma unroll
        for (int r = 0; r < 4; r++) {
          const float x = acc[mi][ni][r];
          const float g = 0.5f * x * (1.f + erff(x * 0.70710678118654752f));
          Hout[(size_t)(rloc + r) * DIM + col] = f2b(g);
        }
      }
    }
  } else {
#pragma unroll
    for (int mi = 0; mi < 4; mi++) {
      const int rbase = m0 + wm * 64 + mi * 16 + grow;
#pragma unroll
      for (int r = 0; r < 4; r++) {
        const int rr = rbase + r;
        const int tok = row_token[rr];
        if (tok < TOK) {
          const float g = row_gate[rr];
          float* op = out + (size_t)tok * DIM + n0 + wn * 64 + lr;
#pragma unroll
          for (int ni = 0; ni < 4; ni++)
            atomicAdd(op + ni * 16, g * acc[mi][ni][r]);
        }
      }
    }
  }
}

extern "C" void kernel_launch(void* const* d_in, const int* in_sizes, int n_in,
                              void* d_out, int out_size, void* d_ws,
                              size_t ws_size, hipStream_t stream) {
  (void)in_sizes; (void)n_in; (void)ws_size;
  const float* tokens = (const float*)d_in[0];
  const float* rw = (const float*)d_in[1];
  const float* w1 = (const float*)d_in[2];
  const float* w2 = (const float*)d_in[3];
  float* out = (float*)d_out;

  char* ws = (char*)d_ws;
  size_t off = 0;
  auto alloc = [&](size_t b) {
    size_t o = off;
    off += (b + 255) & ~(size_t)255;
    return o;
  };
  // ~97 MB total (same footprint class as the passing r8 layout)
  int* ctrl = (int*)(ws + alloc(256));
  int* topi = (int*)(ws + alloc((size_t)TOK * 2 * 4));
  float* topv = (float*)(ws + alloc((size_t)TOK * 2 * 4));
  int* row_token = (int*)(ws + alloc((size_t)BMCAP * 4));
  float* row_gate = (float*)(ws + alloc((size_t)BMCAP * 4));
  ushort_t* w1T = (ushort_t*)(ws + alloc((size_t)NE * DIM * DIM * 2));
  ushort_t* w2T = (ushort_t*)(ws + alloc((size_t)NE * DIM * DIM * 2));
  ushort_t* H = (ushort_t*)(ws + alloc((size_t)CH * DIM * 2));

  hipMemsetAsync(ctrl, 0, 256, stream);
  router_seq<<<TOK / 32, 256, 0, stream>>>(tokens, rw, topi, topv, ctrl);
  prefix_kernel<<<1, 64, 0, stream>>>(ctrl);
  init_rows<<<(BMCAP + 255) / 256, 256, 0, stream>>>(row_token, row_gate);
  assign_kernel<<<TOK / 256, 256, 0, stream>>>(topi, topv, ctrl, row_token,
                                               row_gate);
  dim3 tg(16, 16, 8);
  transpose_cast<<<tg, 256, 0, stream>>>(w1, w1T);
  transpose_cast<<<tg, 256, 0, stream>>>(w2, w2T);
  hipMemsetAsync(out, 0, (size_t)out_size * 4, stream);
  dim3 dg(CH / 128, 8);
  for (int c = 0; c < NCHUNK; c++) {
    dgemm<0><<<dg, 256, 0, stream>>>(tokens, H, w1T, row_token, row_gate, ctrl,
                                     c * CH, H, out);
    dgemm<1><<<dg, 256, 0, stream>>>(tokens, H, w2T, row_token, row_gate, ctrl,
                                     c * CH, H, out);
  }
}

// Round 10
// 1343.713 us; speedup vs baseline: 2.0736x; 1.1222x over previous
//
#include <hip/hip_runtime.h>
#include <hip/hip_bf16.h>
#include <math.h>
#include <stdint.h>

#define TOK 32768
#define DIM 1024
#define NE 8
#define BMCAP (2 * TOK + NE * 128) /* 66560 row slots (segments padded to 128) */
#define CH 32768                   /* H chunk rows */
#define NCHUNK ((BMCAP + CH - 1) / CH) /* 3 */

typedef __attribute__((ext_vector_type(8))) short bf16x8;
typedef __attribute__((ext_vector_type(4))) float f32x4;
typedef unsigned short ushort_t;

__device__ __forceinline__ unsigned short f2b(float x) {
  union { float f; unsigned u; } v; v.f = x;
  unsigned r = v.u + 0x7fffu + ((v.u >> 16) & 1u);
  return (unsigned short)(r >> 16);
}

__device__ __forceinline__ void async16(void* lds, const void* g) {
  auto* lp = (__attribute__((address_space(3))) uint32_t*)lds;
  auto* gp = (__attribute__((address_space(1))) uint32_t*)(const_cast<void*>(g));
  __builtin_amdgcn_global_load_lds(gp, lp, 16, 0, 0);
}

// ---------------- rw [E][K] -> rwT [K][E] (k-major, 32 KB) ------------------
__global__ __launch_bounds__(256) void transpose_rw(
    const float* __restrict__ rw, float* __restrict__ rwT) {
  for (int j = threadIdx.x; j < NE * DIM; j += 256) {
    const int k = j >> 3, e = j & 7;
    rwT[j] = rw[e * DIM + k];
  }
}

// ---- router: STRICTLY SEQUENTIAL f32 FMA chain (FROZEN arithmetic), --------
// ---- rw staged in LDS (k-major, broadcast conflict-free), float4 x ---------
__global__ __launch_bounds__(256) void router_seq2(
    const float* __restrict__ tokens, const float* __restrict__ rwT,
    int* __restrict__ topi, float* __restrict__ topv, int* __restrict__ cnt) {
  __shared__ float wl[NE * DIM];
  __shared__ float sc[256];
  const int tid = threadIdx.x;
  {
    const float4* src4 = (const float4*)rwT;
    float4* dst4 = (float4*)wl;
    for (int i = tid; i < NE * DIM / 4; i += 256) dst4[i] = src4[i];
  }
  __syncthreads();
  const int e = tid & 7;
  const int tr = tid >> 3; /* 0..31 */
  const int t = blockIdx.x * 32 + tr;
  const float4* x4 = (const float4*)(tokens + (size_t)t * DIM);
  float s = 0.f;
#pragma unroll 8
  for (int k4 = 0; k4 < DIM / 4; k4++) {
    const float4 xv = x4[k4];
    const int kb = k4 << 2;
    s = fmaf(xv.x, wl[(kb + 0) * 8 + e], s);
    s = fmaf(xv.y, wl[(kb + 1) * 8 + e], s);
    s = fmaf(xv.z, wl[(kb + 2) * 8 + e], s);
    s = fmaf(xv.w, wl[(kb + 3) * 8 + e], s);
  }
  sc[tid] = s;
  __syncthreads();
  if (e == 0) {
    float p[NE];
    float m = sc[tr * 8];
#pragma unroll
    for (int i = 1; i < NE; i++) m = fmaxf(m, sc[tr * 8 + i]);
    float sum = 0.f;
#pragma unroll
    for (int i = 0; i < NE; i++) {
      p[i] = expf(sc[tr * 8 + i] - m);
      sum += p[i];
    }
#pragma unroll
    for (int i = 0; i < NE; i++) p[i] = p[i] / sum;
    int e0 = 0;
#pragma unroll
    for (int i = 1; i < NE; i++) if (p[i] > p[e0]) e0 = i;
    int e1 = (e0 == 0) ? 1 : 0;
#pragma unroll
    for (int i = 0; i < NE; i++) if (i != e0 && p[i] > p[e1]) e1 = i;
    topi[t * 2] = e0;     topv[t * 2] = p[e0];
    topi[t * 2 + 1] = e1; topv[t * 2 + 1] = p[e1];
    atomicAdd(&cnt[e0], 1);
    atomicAdd(&cnt[e1], 1);
  }
}

// ---------------- tokens f32 -> bf16 (same RNE as in-GEMM cvt) --------------
__global__ __launch_bounds__(256) void cast_tokens(
    const float* __restrict__ t, ushort_t* __restrict__ x16) {
  const size_t i = ((size_t)blockIdx.x * 256 + threadIdx.x) * 8;
  const float4 a = *(const float4*)(t + i);
  const float4 b = *(const float4*)(t + i + 4);
  bf16x8 h;
  h[0] = (short)f2b(a.x); h[1] = (short)f2b(a.y);
  h[2] = (short)f2b(a.z); h[3] = (short)f2b(a.w);
  h[4] = (short)f2b(b.x); h[5] = (short)f2b(b.y);
  h[6] = (short)f2b(b.z); h[7] = (short)f2b(b.w);
  *(bf16x8*)(x16 + i) = h;
}

// ---------------- weights: [E][K][N] f32 -> [E][N][K] bf16 (B^T layout) -----
__global__ __launch_bounds__(256) void transpose_cast(
    const float* __restrict__ w, ushort_t* __restrict__ wT) {
  __shared__ float tile[64][65];
  const int e = blockIdx.z;
  const int n0 = blockIdx.x * 64, k0 = blockIdx.y * 64;
  const int tx = threadIdx.x & 63, ty = threadIdx.x >> 6;
  const float* src = w + ((size_t)e << 20);
  ushort_t* dst = wT + ((size_t)e << 20);
#pragma unroll
  for (int r = ty; r < 64; r += 4)
    tile[r][tx] = src[(size_t)(k0 + r) * DIM + n0 + tx];
  __syncthreads();
#pragma unroll
  for (int r = ty; r < 64; r += 4)
    dst[(size_t)(n0 + r) * DIM + k0 + tx] = f2b(tile[tx][r]);
}

// ---------------- ctrl: [0..7] count, [8..15] cursor, [16..24] seg_start ----
__global__ void prefix_kernel(int* ctrl) {
  if (threadIdx.x == 0 && blockIdx.x == 0) {
    int s = 0;
    for (int e = 0; e < NE; e++) {
      ctrl[16 + e] = s;
      ctrl[8 + e] = s;
      s += (ctrl[e] + 127) & ~127;
    }
    ctrl[24] = s; /* Mpad */
  }
}

__global__ __launch_bounds__(256) void init_rows(
    int* __restrict__ row_token, float* __restrict__ row_gate) {
  const int i = blockIdx.x * 256 + threadIdx.x;
  if (i < BMCAP) { row_token[i] = TOK; row_gate[i] = 0.f; }
}

__global__ __launch_bounds__(256) void assign_kernel(
    const int* __restrict__ topi, const float* __restrict__ topv,
    int* __restrict__ ctrl, int* __restrict__ row_token,
    float* __restrict__ row_gate) {
  const int t = blockIdx.x * 256 + threadIdx.x;
  if (t >= TOK) return;
#pragma unroll
  for (int k = 0; k < 2; k++) {
    const int e = topi[t * 2 + k];
    const int pos = atomicAdd(&ctrl[8 + e], 1);
    row_token[pos] = t;
    row_gate[pos] = topv[t * 2 + k];
  }
}

// ------- grouped GEMM, 128x128 tile, BK=32, 4 waves, H chunked --------------
// PASS 0: H[r-cbase,:] = gelu( X16[row_token[r],:] @ wT[e]^T )   (bf16 out)
// PASS 1: out[row_token[r],:] += row_gate[r] * ( H[r-cbase,:] @ wT[e]^T )
template <int PASS>
__global__ __launch_bounds__(256) void dgemm(
    const ushort_t* __restrict__ Asrc, const ushort_t* __restrict__ Wt,
    const int* __restrict__ row_token, const float* __restrict__ row_gate,
    const int* __restrict__ ctrl, int cbase, ushort_t* __restrict__ Hout,
    float* __restrict__ out) {
  const int Mpad = ctrl[24];
  const int m0 = cbase + blockIdx.x * 128;
  if (m0 >= Mpad) return;
  const int m0loc = m0 - cbase;
  const int n0 = blockIdx.y * 128;
  int e = 0;
#pragma unroll
  for (int i = 0; i < NE - 1; i++)
    if (m0 >= ctrl[16 + i + 1]) e = i + 1;
  const ushort_t* B = Wt + ((size_t)e << 20);

  __shared__ ushort_t As[128 * 32];
  __shared__ ushort_t Bs[128 * 32];
  const int tid = threadIdx.x;
  const int lane = tid & 63;
  const int wave = tid >> 6;
  const int wm = wave >> 1, wn = wave & 1;
  const int lr = lane & 15;
  const int lk = (lane >> 4) << 3;

  const ushort_t* asrc0;
  const ushort_t* asrc1;
  if (PASS == 0) {
    int tk0 = row_token[m0 + (tid >> 2)];
    int tk1 = row_token[m0 + 64 + (tid >> 2)];
    if (tk0 >= TOK) tk0 = 0; /* pad rows: any valid row, result unused */
    if (tk1 >= TOK) tk1 = 0;
    asrc0 = Asrc + (size_t)tk0 * DIM + ((tid & 3) << 3);
    asrc1 = Asrc + (size_t)tk1 * DIM + ((tid & 3) << 3);
  } else {
    asrc0 = Asrc + (size_t)(m0loc + (tid >> 2)) * DIM + ((tid & 3) << 3);
    asrc1 = Asrc + (size_t)(m0loc + 64 + (tid >> 2)) * DIM + ((tid & 3) << 3);
  }
  const ushort_t* bsrc0 = B + (size_t)(n0 + (tid >> 2)) * DIM + ((tid & 3) << 3);
  const ushort_t* bsrc1 =
      B + (size_t)(n0 + 64 + (tid >> 2)) * DIM + ((tid & 3) << 3);
  ushort_t* lA0 = &As[(tid & ~63) * 8];
  ushort_t* lA1 = &As[(256 + (tid & ~63)) * 8];
  ushort_t* lB0 = &Bs[(tid & ~63) * 8];
  ushort_t* lB1 = &Bs[(256 + (tid & ~63)) * 8];

  f32x4 acc[4][4] = {};

  for (int k0 = 0; k0 < DIM; k0 += 32) {
    async16(lA0, asrc0 + k0);
    async16(lA1, asrc1 + k0);
    async16(lB0, bsrc0 + k0);
    async16(lB1, bsrc1 + k0);
    __syncthreads();
    bf16x8 a[4], b[4];
#pragma unroll
    for (int i = 0; i < 4; i++)
      a[i] = *(const bf16x8*)&As[(wm * 64 + i * 16 + lr) * 32 + lk];
#pragma unroll
    for (int i = 0; i < 4; i++)
      b[i] = *(const bf16x8*)&Bs[(wn * 64 + i * 16 + lr) * 32 + lk];
#pragma unroll
    for (int mi = 0; mi < 4; mi++)
#pragma unroll
      for (int ni = 0; ni < 4; ni++)
        acc[mi][ni] = __builtin_amdgcn_mfma_f32_16x16x32_bf16(
            a[mi], b[ni], acc[mi][ni], 0, 0, 0);
    __syncthreads();
  }

  const int grow = (lane >> 4) << 2;
  if (PASS == 0) {
#pragma unroll
    for (int mi = 0; mi < 4; mi++) {
      const int rloc = m0loc + wm * 64 + mi * 16 + grow;
#pragma unroll
      for (int ni = 0; ni < 4; ni++) {
        const int col = n0 + wn * 64 + ni * 16 + lr;
#pragma unroll
        for (int r = 0; r < 4; r++) {
          const float x = acc[mi][ni][r];
          const float g = 0.5f * x * (1.f + erff(x * 0.70710678118654752f));
          Hout[(size_t)(rloc + r) * DIM + col] = f2b(g);
        }
      }
    }
  } else {
#pragma unroll
    for (int mi = 0; mi < 4; mi++) {
      const int rbase = m0 + wm * 64 + mi * 16 + grow;
#pragma unroll
      for (int r = 0; r < 4; r++) {
        const int rr = rbase + r;
        const int tok = row_token[rr];
        if (tok < TOK) {
          const float g = row_gate[rr];
          float* op = out + (size_t)tok * DIM + n0 + wn * 64 + lr;
#pragma unroll
          for (int ni = 0; ni < 4; ni++)
            atomicAdd(op + ni * 16, g * acc[mi][ni][r]);
        }
      }
    }
  }
}

extern "C" void kernel_launch(void* const* d_in, const int* in_sizes, int n_in,
                              void* d_out, int out_size, void* d_ws,
                              size_t ws_size, hipStream_t stream) {
  (void)in_sizes; (void)n_in; (void)ws_size;
  const float* tokens = (const float*)d_in[0];
  const float* rw = (const float*)d_in[1];
  const float* w1 = (const float*)d_in[2];
  const float* w2 = (const float*)d_in[3];
  float* out = (float*)d_out;

  char* ws = (char*)d_ws;
  size_t off = 0;
  auto alloc = [&](size_t b) {
    size_t o = off;
    off += (b + 255) & ~(size_t)255;
    return o;
  };
  // ~162 MB total
  int* ctrl = (int*)(ws + alloc(256));
  int* topi = (int*)(ws + alloc((size_t)TOK * 2 * 4));
  float* topv = (float*)(ws + alloc((size_t)TOK * 2 * 4));
  int* row_token = (int*)(ws + alloc((size_t)BMCAP * 4));
  float* row_gate = (float*)(ws + alloc((size_t)BMCAP * 4));
  float* rwT = (float*)(ws + alloc((size_t)NE * DIM * 4));
  ushort_t* X16 = (ushort_t*)(ws + alloc((size_t)TOK * DIM * 2));
  ushort_t* w1T = (ushort_t*)(ws + alloc((size_t)NE * DIM * DIM * 2));
  ushort_t* w2T = (ushort_t*)(ws + alloc((size_t)NE * DIM * DIM * 2));
  ushort_t* H = (ushort_t*)(ws + alloc((size_t)CH * DIM * 2));

  hipMemsetAsync(ctrl, 0, 256, stream);
  transpose_rw<<<1, 256, 0, stream>>>(rw, rwT);
  router_seq2<<<TOK / 32, 256, 0, stream>>>(tokens, rwT, topi, topv, ctrl);
  prefix_kernel<<<1, 64, 0, stream>>>(ctrl);
  init_rows<<<(BMCAP + 255) / 256, 256, 0, stream>>>(row_token, row_gate);
  assign_kernel<<<TOK / 256, 256, 0, stream>>>(topi, topv, ctrl, row_token,
                                               row_gate);
  cast_tokens<<<TOK * DIM / 8 / 256, 256, 0, stream>>>(tokens, X16);
  dim3 tg(16, 16, 8);
  transpose_cast<<<tg, 256, 0, stream>>>(w1, w1T);
  transpose_cast<<<tg, 256, 0, stream>>>(w2, w2T);
  hipMemsetAsync(out, 0, (size_t)out_size * 4, stream);
  dim3 dg(CH / 128, 8);
  for (int c = 0; c < NCHUNK; c++) {
    dgemm<0><<<dg, 256, 0, stream>>>(X16, w1T, row_token, row_gate, ctrl,
                                     c * CH, H, out);
    dgemm<1><<<dg, 256, 0, stream>>>(H, w2T, row_token, row_gate, ctrl, c * CH,
                                     H, out);
  }
}

// Round 11
// 1321.181 us; speedup vs baseline: 2.1090x; 1.0171x over previous
//
#include <hip/hip_runtime.h>
#include <hip/hip_bf16.h>
#include <math.h>
#include <stdint.h>

#define TOK 32768
#define DIM 1024
#define NE 8
#define BMCAP (2 * TOK + NE * 128) /* 66560 row slots (segments padded to 128) */
#define CH 32768                   /* H chunk rows */
#define NCHUNK ((BMCAP + CH - 1) / CH) /* 3 */

typedef __attribute__((ext_vector_type(8))) short bf16x8;
typedef __attribute__((ext_vector_type(4))) float f32x4;
typedef unsigned short ushort_t;

__device__ __forceinline__ unsigned short f2b(float x) {
  union { float f; unsigned u; } v; v.f = x;
  unsigned r = v.u + 0x7fffu + ((v.u >> 16) & 1u);
  return (unsigned short)(r >> 16);
}

__device__ __forceinline__ void async16(void* lds, const void* g) {
  auto* lp = (__attribute__((address_space(3))) uint32_t*)lds;
  auto* gp = (__attribute__((address_space(1))) uint32_t*)(const_cast<void*>(g));
  __builtin_amdgcn_global_load_lds(gp, lp, 16, 0, 0);
}

// ---- router v3: chunked double-buffered LDS staging; FROZEN fmaf chain -----
// 32 tokens/block, 8 experts/token. k-chunks of 128, x and w staged via
// reg (issue-early) -> LDS (write-late, padded rows = conflict-free reads).
// Arithmetic identical to r8-r10: s = fmaf(x[k], w[k], s), k = 0..1023.
__global__ __launch_bounds__(256) void router_seq3(
    const float* __restrict__ tokens, const float* __restrict__ rw,
    int* __restrict__ topi, float* __restrict__ topv, int* __restrict__ cnt) {
  __shared__ float xs[2][32][132]; /* pad 128->132: bank-spread reads */
  __shared__ float wsh[2][8][132];
  __shared__ float sc[256];
  const int tid = threadIdx.x;
  const int e = tid & 7;
  const int tr = tid >> 3; /* 0..31 */
  const int t0 = blockIdx.x * 32;

  float4 lx0, lx1, lx2, lx3, lw;
  auto issue = [&](int c) {
    const int col = (tid & 31) * 4;
    lx0 = *(const float4*)&tokens[(size_t)(t0 + ((tid + 0) >> 5)) * DIM + c * 128 + col];
    lx1 = *(const float4*)&tokens[(size_t)(t0 + ((tid + 256) >> 5)) * DIM + c * 128 + col];
    lx2 = *(const float4*)&tokens[(size_t)(t0 + ((tid + 512) >> 5)) * DIM + c * 128 + col];
    lx3 = *(const float4*)&tokens[(size_t)(t0 + ((tid + 768) >> 5)) * DIM + c * 128 + col];
    lw  = *(const float4*)&rw[(size_t)(tid >> 5) * DIM + c * 128 + col];
  };
  auto commit = [&](int b) {
    const int col = (tid & 31) * 4;
    *(float4*)&xs[b][(tid + 0) >> 5][col] = lx0;
    *(float4*)&xs[b][(tid + 256) >> 5][col] = lx1;
    *(float4*)&xs[b][(tid + 512) >> 5][col] = lx2;
    *(float4*)&xs[b][(tid + 768) >> 5][col] = lx3;
    *(float4*)&wsh[b][tid >> 5][col] = lw;
  };

  issue(0);
  commit(0);
  __syncthreads();
  float s = 0.f;
  for (int c = 0; c < 8; c++) {
    const int b = c & 1;
    if (c + 1 < 8) issue(c + 1);
#pragma unroll
    for (int k4 = 0; k4 < 32; k4++) {
      const float4 xv = *(const float4*)&xs[b][tr][k4 * 4];
      const float4 wv = *(const float4*)&wsh[b][e][k4 * 4];
      s = fmaf(xv.x, wv.x, s);
      s = fmaf(xv.y, wv.y, s);
      s = fmaf(xv.z, wv.z, s);
      s = fmaf(xv.w, wv.w, s);
    }
    if (c + 1 < 8) commit(b ^ 1);
    __syncthreads();
  }
  sc[tid] = s;
  __syncthreads();
  if (e == 0) {
    float p[NE];
    float m = sc[tr * 8];
#pragma unroll
    for (int i = 1; i < NE; i++) m = fmaxf(m, sc[tr * 8 + i]);
    float sum = 0.f;
#pragma unroll
    for (int i = 0; i < NE; i++) {
      p[i] = expf(sc[tr * 8 + i] - m);
      sum += p[i];
    }
#pragma unroll
    for (int i = 0; i < NE; i++) p[i] = p[i] / sum;
    const int t = t0 + tr;
    int e0 = 0;
#pragma unroll
    for (int i = 1; i < NE; i++) if (p[i] > p[e0]) e0 = i;
    int e1 = (e0 == 0) ? 1 : 0;
#pragma unroll
    for (int i = 0; i < NE; i++) if (i != e0 && p[i] > p[e1]) e1 = i;
    topi[t * 2] = e0;     topv[t * 2] = p[e0];
    topi[t * 2 + 1] = e1; topv[t * 2 + 1] = p[e1];
    atomicAdd(&cnt[e0], 1);
    atomicAdd(&cnt[e1], 1);
  }
}

// ---------------- tokens f32 -> bf16 (same RNE as in-GEMM cvt) --------------
__global__ __launch_bounds__(256) void cast_tokens(
    const float* __restrict__ t, ushort_t* __restrict__ x16) {
  const size_t i = ((size_t)blockIdx.x * 256 + threadIdx.x) * 8;
  const float4 a = *(const float4*)(t + i);
  const float4 b = *(const float4*)(t + i + 4);
  bf16x8 h;
  h[0] = (short)f2b(a.x); h[1] = (short)f2b(a.y);
  h[2] = (short)f2b(a.z); h[3] = (short)f2b(a.w);
  h[4] = (short)f2b(b.x); h[5] = (short)f2b(b.y);
  h[6] = (short)f2b(b.z); h[7] = (short)f2b(b.w);
  *(bf16x8*)(x16 + i) = h;
}

// ---------------- weights: [E][K][N] f32 -> [E][N][K] bf16 (B^T layout) -----
__global__ __launch_bounds__(256) void transpose_cast(
    const float* __restrict__ w, ushort_t* __restrict__ wT) {
  __shared__ float tile[64][65];
  const int e = blockIdx.z;
  const int n0 = blockIdx.x * 64, k0 = blockIdx.y * 64;
  const int tx = threadIdx.x & 63, ty = threadIdx.x >> 6;
  const float* src = w + ((size_t)e << 20);
  ushort_t* dst = wT + ((size_t)e << 20);
#pragma unroll
  for (int r = ty; r < 64; r += 4)
    tile[r][tx] = src[(size_t)(k0 + r) * DIM + n0 + tx];
  __syncthreads();
#pragma unroll
  for (int r = ty; r < 64; r += 4)
    dst[(size_t)(n0 + r) * DIM + k0 + tx] = f2b(tile[tx][r]);
}

// ---------------- ctrl: [0..7] count, [8..15] cursor, [16..24] seg_start ----
__global__ void prefix_kernel(int* ctrl) {
  if (threadIdx.x == 0 && blockIdx.x == 0) {
    int s = 0;
    for (int e = 0; e < NE; e++) {
      ctrl[16 + e] = s;
      ctrl[8 + e] = s;
      s += (ctrl[e] + 127) & ~127;
    }
    ctrl[24] = s; /* Mpad */
  }
}

__global__ __launch_bounds__(256) void init_rows(
    int* __restrict__ row_token, float* __restrict__ row_gate) {
  const int i = blockIdx.x * 256 + threadIdx.x;
  if (i < BMCAP) { row_token[i] = TOK; row_gate[i] = 0.f; }
}

__global__ __launch_bounds__(256) void assign_kernel(
    const int* __restrict__ topi, const float* __restrict__ topv,
    int* __restrict__ ctrl, int* __restrict__ row_token,
    float* __restrict__ row_gate) {
  const int t = blockIdx.x * 256 + threadIdx.x;
  if (t >= TOK) return;
#pragma unroll
  for (int k = 0; k < 2; k++) {
    const int e = topi[t * 2 + k];
    const int pos = atomicAdd(&ctrl[8 + e], 1);
    row_token[pos] = t;
    row_gate[pos] = topv[t * 2 + k];
  }
}

// ------- grouped GEMM, 128x128 tile, BK=32, 4 waves, H chunked --------------
// PASS 0: H[r-cbase,:] = gelu( X16[row_token[r],:] @ wT[e]^T )   (bf16 out)
// PASS 1: out[row_token[r],:] += row_gate[r] * ( H[r-cbase,:] @ wT[e]^T )
template <int PASS>
__global__ __launch_bounds__(256) void dgemm(
    const ushort_t* __restrict__ Asrc, const ushort_t* __restrict__ Wt,
    const int* __restrict__ row_token, const float* __restrict__ row_gate,
    const int* __restrict__ ctrl, int cbase, ushort_t* __restrict__ Hout,
    float* __restrict__ out) {
  const int Mpad = ctrl[24];
  const int m0 = cbase + blockIdx.x * 128;
  if (m0 >= Mpad) return;
  const int m0loc = m0 - cbase;
  const int n0 = blockIdx.y * 128;
  int e = 0;
#pragma unroll
  for (int i = 0; i < NE - 1; i++)
    if (m0 >= ctrl[16 + i + 1]) e = i + 1;
  const ushort_t* B = Wt + ((size_t)e << 20);

  __shared__ ushort_t As[128 * 32];
  __shared__ ushort_t Bs[128 * 32];
  const int tid = threadIdx.x;
  const int lane = tid & 63;
  const int wave = tid >> 6;
  const int wm = wave >> 1, wn = wave & 1;
  const int lr = lane & 15;
  const int lk = (lane >> 4) << 3;

  const ushort_t* asrc0;
  const ushort_t* asrc1;
  if (PASS == 0) {
    int tk0 = row_token[m0 + (tid >> 2)];
    int tk1 = row_token[m0 + 64 + (tid >> 2)];
    if (tk0 >= TOK) tk0 = 0; /* pad rows: any valid row, result unused */
    if (tk1 >= TOK) tk1 = 0;
    asrc0 = Asrc + (size_t)tk0 * DIM + ((tid & 3) << 3);
    asrc1 = Asrc + (size_t)tk1 * DIM + ((tid & 3) << 3);
  } else {
    asrc0 = Asrc + (size_t)(m0loc + (tid >> 2)) * DIM + ((tid & 3) << 3);
    asrc1 = Asrc + (size_t)(m0loc + 64 + (tid >> 2)) * DIM + ((tid & 3) << 3);
  }
  const ushort_t* bsrc0 = B + (size_t)(n0 + (tid >> 2)) * DIM + ((tid & 3) << 3);
  const ushort_t* bsrc1 =
      B + (size_t)(n0 + 64 + (tid >> 2)) * DIM + ((tid & 3) << 3);
  ushort_t* lA0 = &As[(tid & ~63) * 8];
  ushort_t* lA1 = &As[(256 + (tid & ~63)) * 8];
  ushort_t* lB0 = &Bs[(tid & ~63) * 8];
  ushort_t* lB1 = &Bs[(256 + (tid & ~63)) * 8];

  f32x4 acc[4][4] = {};

  for (int k0 = 0; k0 < DIM; k0 += 32) {
    async16(lA0, asrc0 + k0);
    async16(lA1, asrc1 + k0);
    async16(lB0, bsrc0 + k0);
    async16(lB1, bsrc1 + k0);
    __syncthreads();
    bf16x8 a[4], b[4];
#pragma unroll
    for (int i = 0; i < 4; i++)
      a[i] = *(const bf16x8*)&As[(wm * 64 + i * 16 + lr) * 32 + lk];
#pragma unroll
    for (int i = 0; i < 4; i++)
      b[i] = *(const bf16x8*)&Bs[(wn * 64 + i * 16 + lr) * 32 + lk];
#pragma unroll
    for (int mi = 0; mi < 4; mi++)
#pragma unroll
      for (int ni = 0; ni < 4; ni++)
        acc[mi][ni] = __builtin_amdgcn_mfma_f32_16x16x32_bf16(
            a[mi], b[ni], acc[mi][ni], 0, 0, 0);
    __syncthreads();
  }

  const int grow = (lane >> 4) << 2;
  if (PASS == 0) {
#pragma unroll
    for (int mi = 0; mi < 4; mi++) {
      const int rloc = m0loc + wm * 64 + mi * 16 + grow;
#pragma unroll
      for (int ni = 0; ni < 4; ni++) {
        const int col = n0 + wn * 64 + ni * 16 + lr;
#pragma unroll
        for (int r = 0; r < 4; r++) {
          const float x = acc[mi][ni][r];
          const float g = 0.5f * x * (1.f + erff(x * 0.70710678118654752f));
          Hout[(size_t)(rloc + r) * DIM + col] = f2b(g);
        }
      }
    }
  } else {
#pragma unroll
    for (int mi = 0; mi < 4; mi++) {
      const int rbase = m0 + wm * 64 + mi * 16 + grow;
#pragma unroll
      for (int r = 0; r < 4; r++) {
        const int rr = rbase + r;
        const int tok = row_token[rr];
        if (tok < TOK) {
          const float g = row_gate[rr];
          float* op = out + (size_t)tok * DIM + n0 + wn * 64 + lr;
#pragma unroll
          for (int ni = 0; ni < 4; ni++)
            atomicAdd(op + ni * 16, g * acc[mi][ni][r]);
        }
      }
    }
  }
}

extern "C" void kernel_launch(void* const* d_in, const int* in_sizes, int n_in,
                              void* d_out, int out_size, void* d_ws,
                              size_t ws_size, hipStream_t stream) {
  (void)in_sizes; (void)n_in; (void)ws_size;
  const float* tokens = (const float*)d_in[0];
  const float* rw = (const float*)d_in[1];
  const float* w1 = (const float*)d_in[2];
  const float* w2 = (const float*)d_in[3];
  float* out = (float*)d_out;

  char* ws = (char*)d_ws;
  size_t off = 0;
  auto alloc = [&](size_t b) {
    size_t o = off;
    off += (b + 255) & ~(size_t)255;
    return o;
  };
  int* ctrl = (int*)(ws + alloc(256));
  int* topi = (int*)(ws + alloc((size_t)TOK * 2 * 4));
  float* topv = (float*)(ws + alloc((size_t)TOK * 2 * 4));
  int* row_token = (int*)(ws + alloc((size_t)BMCAP * 4));
  float* row_gate = (float*)(ws + alloc((size_t)BMCAP * 4));
  ushort_t* X16 = (ushort_t*)(ws + alloc((size_t)TOK * DIM * 2));
  ushort_t* w1T = (ushort_t*)(ws + alloc((size_t)NE * DIM * DIM * 2));
  ushort_t* w2T = (ushort_t*)(ws + alloc((size_t)NE * DIM * DIM * 2));
  ushort_t* H = (ushort_t*)(ws + alloc((size_t)CH * DIM * 2));

  hipMemsetAsync(ctrl, 0, 256, stream);
  router_seq3<<<TOK / 32, 256, 0, stream>>>(tokens, rw, topi, topv, ctrl);
  prefix_kernel<<<1, 64, 0, stream>>>(ctrl);
  init_rows<<<(BMCAP + 255) / 256, 256, 0, stream>>>(row_token, row_gate);
  assign_kernel<<<TOK / 256, 256, 0, stream>>>(topi, topv, ctrl, row_token,
                                               row_gate);
  cast_tokens<<<TOK * DIM / 8 / 256, 256, 0, stream>>>(tokens, X16);
  dim3 tg(16, 16, 8);
  transpose_cast<<<tg, 256, 0, stream>>>(w1, w1T);
  transpose_cast<<<tg, 256, 0, stream>>>(w2, w2T);
  hipMemsetAsync(out, 0, (size_t)out_size * 4, stream);
  dim3 dg(CH / 128, 8);
  for (int c = 0; c < NCHUNK; c++) {
    dgemm<0><<<dg, 256, 0, stream>>>(X16, w1T, row_token, row_gate, ctrl,
                                     c * CH, H, out);
    dgemm<1><<<dg, 256, 0, stream>>>(H, w2T, row_token, row_gate, ctrl, c * CH,
                                     H, out);
  }
}

// Round 12
// 780.330 us; speedup vs baseline: 3.5708x; 1.6931x over previous
//
#include <hip/hip_runtime.h>
#include <hip/hip_bf16.h>
#include <math.h>
#include <stdint.h>

#define TOK 32768
#define DIM 1024
#define NE 8
#define BMCAP (2 * TOK + NE * 128) /* 66560 row slots (segments padded to 128) */
#define CH 32768                   /* H chunk rows */
#define NCHUNK ((BMCAP + CH - 1) / CH) /* 3 */

// ctrl layout (ints): cnt[e] @ e*16 ; cursor[e] @ 128+e*16 ; seg_start[e] @ 256+e ; Mpad @ 264
#define C_CNT(e) ((e) * 16)
#define C_CUR(e) (128 + (e) * 16)
#define C_SEG(e) (256 + (e))
#define C_MPAD 264

typedef __attribute__((ext_vector_type(8))) short bf16x8;
typedef __attribute__((ext_vector_type(4))) float f32x4;
typedef unsigned short ushort_t;

__device__ __forceinline__ unsigned short f2b(float x) {
  union { float f; unsigned u; } v; v.f = x;
  unsigned r = v.u + 0x7fffu + ((v.u >> 16) & 1u);
  return (unsigned short)(r >> 16);
}

__device__ __forceinline__ void async16(void* lds, const void* g) {
  auto* lp = (__attribute__((address_space(3))) uint32_t*)lds;
  auto* gp = (__attribute__((address_space(1))) uint32_t*)(const_cast<void*>(g));
  __builtin_amdgcn_global_load_lds(gp, lp, 16, 0, 0);
}

// ---- router v3 minus atomics: FROZEN sequential fmaf chain -----------------
__global__ __launch_bounds__(256) void router_seq3(
    const float* __restrict__ tokens, const float* __restrict__ rw,
    int* __restrict__ topi, float* __restrict__ topv) {
  __shared__ float xs[2][32][132];
  __shared__ float wsh[2][8][132];
  __shared__ float sc[256];
  const int tid = threadIdx.x;
  const int e = tid & 7;
  const int tr = tid >> 3;
  const int t0 = blockIdx.x * 32;

  float4 lx0, lx1, lx2, lx3, lw;
  auto issue = [&](int c) {
    const int col = (tid & 31) * 4;
    lx0 = *(const float4*)&tokens[(size_t)(t0 + ((tid + 0) >> 5)) * DIM + c * 128 + col];
    lx1 = *(const float4*)&tokens[(size_t)(t0 + ((tid + 256) >> 5)) * DIM + c * 128 + col];
    lx2 = *(const float4*)&tokens[(size_t)(t0 + ((tid + 512) >> 5)) * DIM + c * 128 + col];
    lx3 = *(const float4*)&tokens[(size_t)(t0 + ((tid + 768) >> 5)) * DIM + c * 128 + col];
    lw  = *(const float4*)&rw[(size_t)(tid >> 5) * DIM + c * 128 + col];
  };
  auto commit = [&](int b) {
    const int col = (tid & 31) * 4;
    *(float4*)&xs[b][(tid + 0) >> 5][col] = lx0;
    *(float4*)&xs[b][(tid + 256) >> 5][col] = lx1;
    *(float4*)&xs[b][(tid + 512) >> 5][col] = lx2;
    *(float4*)&xs[b][(tid + 768) >> 5][col] = lx3;
    *(float4*)&wsh[b][tid >> 5][col] = lw;
  };

  issue(0);
  commit(0);
  __syncthreads();
  float s = 0.f;
  for (int c = 0; c < 8; c++) {
    const int b = c & 1;
    if (c + 1 < 8) issue(c + 1);
#pragma unroll
    for (int k4 = 0; k4 < 32; k4++) {
      const float4 xv = *(const float4*)&xs[b][tr][k4 * 4];
      const float4 wv = *(const float4*)&wsh[b][e][k4 * 4];
      s = fmaf(xv.x, wv.x, s);
      s = fmaf(xv.y, wv.y, s);
      s = fmaf(xv.z, wv.z, s);
      s = fmaf(xv.w, wv.w, s);
    }
    if (c + 1 < 8) commit(b ^ 1);
    __syncthreads();
  }
  sc[tid] = s;
  __syncthreads();
  if (e == 0) {
    float p[NE];
    float m = sc[tr * 8];
#pragma unroll
    for (int i = 1; i < NE; i++) m = fmaxf(m, sc[tr * 8 + i]);
    float sum = 0.f;
#pragma unroll
    for (int i = 0; i < NE; i++) {
      p[i] = expf(sc[tr * 8 + i] - m);
      sum += p[i];
    }
#pragma unroll
    for (int i = 0; i < NE; i++) p[i] = p[i] / sum;
    const int t = t0 + tr;
    int e0 = 0;
#pragma unroll
    for (int i = 1; i < NE; i++) if (p[i] > p[e0]) e0 = i;
    int e1 = (e0 == 0) ? 1 : 0;
#pragma unroll
    for (int i = 0; i < NE; i++) if (i != e0 && p[i] > p[e1]) e1 = i;
    topi[t * 2] = e0;     topv[t * 2] = p[e0];
    topi[t * 2 + 1] = e1; topv[t * 2 + 1] = p[e1];
  }
}

// ---- per-expert counts: LDS histogram -> padded global counters ------------
__global__ __launch_bounds__(256) void hist_kernel(const int* __restrict__ topi,
                                                   int* __restrict__ ctrl) {
  __shared__ int h[NE];
  const int tid = threadIdx.x;
  if (tid < NE) h[tid] = 0;
  __syncthreads();
  const int base = blockIdx.x * 512;
  atomicAdd(&h[topi[base + tid]], 1);
  atomicAdd(&h[topi[base + 256 + tid]], 1);
  __syncthreads();
  if (tid < NE) atomicAdd(&ctrl[C_CNT(tid)], h[tid]);
}

__global__ void prefix_kernel(int* ctrl) {
  if (threadIdx.x == 0 && blockIdx.x == 0) {
    int s = 0;
    for (int e = 0; e < NE; e++) {
      ctrl[C_SEG(e)] = s;
      ctrl[C_CUR(e)] = s;
      s += (ctrl[C_CNT(e)] + 127) & ~127;
    }
    ctrl[C_MPAD] = s;
  }
}

__global__ __launch_bounds__(256) void init_rows(
    int* __restrict__ row_token, float* __restrict__ row_gate) {
  const int i = blockIdx.x * 256 + threadIdx.x;
  if (i < BMCAP) { row_token[i] = TOK; row_gate[i] = 0.f; }
}

// ---- assign v2: LDS-aggregated ranged reservation (8 atomics/block) --------
__global__ __launch_bounds__(256) void assign2(
    const int* __restrict__ topi, const float* __restrict__ topv,
    int* __restrict__ ctrl, int* __restrict__ row_token,
    float* __restrict__ row_gate) {
  __shared__ int h[NE];
  __shared__ int base[NE];
  const int tid = threadIdx.x;
  const int t = blockIdx.x * 256 + tid;
  if (tid < NE) h[tid] = 0;
  __syncthreads();
  const int e0 = topi[t * 2], e1 = topi[t * 2 + 1];
  const int o0 = atomicAdd(&h[e0], 1);
  const int o1 = atomicAdd(&h[e1], 1);
  __syncthreads();
  if (tid < NE) base[tid] = atomicAdd(&ctrl[C_CUR(tid)], h[tid]);
  __syncthreads();
  const int p0 = base[e0] + o0, p1 = base[e1] + o1;
  row_token[p0] = t; row_gate[p0] = topv[t * 2];
  row_token[p1] = t; row_gate[p1] = topv[t * 2 + 1];
}

// ---------------- tokens f32 -> bf16 ----------------------------------------
__global__ __launch_bounds__(256) void cast_tokens(
    const float* __restrict__ t, ushort_t* __restrict__ x16) {
  const size_t i = ((size_t)blockIdx.x * 256 + threadIdx.x) * 8;
  const float4 a = *(const float4*)(t + i);
  const float4 b = *(const float4*)(t + i + 4);
  bf16x8 h;
  h[0] = (short)f2b(a.x); h[1] = (short)f2b(a.y);
  h[2] = (short)f2b(a.z); h[3] = (short)f2b(a.w);
  h[4] = (short)f2b(b.x); h[5] = (short)f2b(b.y);
  h[6] = (short)f2b(b.z); h[7] = (short)f2b(b.w);
  *(bf16x8*)(x16 + i) = h;
}

// ---------------- weights: [E][K][N] f32 -> [E][N][K] bf16 ------------------
__global__ __launch_bounds__(256) void transpose_cast(
    const float* __restrict__ w, ushort_t* __restrict__ wT) {
  __shared__ float tile[64][65];
  const int e = blockIdx.z;
  const int n0 = blockIdx.x * 64, k0 = blockIdx.y * 64;
  const int tx = threadIdx.x & 63, ty = threadIdx.x >> 6;
  const float* src = w + ((size_t)e << 20);
  ushort_t* dst = wT + ((size_t)e << 20);
#pragma unroll
  for (int r = ty; r < 64; r += 4)
    tile[r][tx] = src[(size_t)(k0 + r) * DIM + n0 + tx];
  __syncthreads();
#pragma unroll
  for (int r = ty; r < 64; r += 4)
    dst[(size_t)(n0 + r) * DIM + k0 + tx] = f2b(tile[tx][r]);
}

// ------- grouped GEMM, 128x128, BK=32, XCD-chunked swizzle, n-fastest -------
template <int PASS>
__global__ __launch_bounds__(256) void dgemm(
    const ushort_t* __restrict__ Asrc, const ushort_t* __restrict__ Wt,
    const int* __restrict__ row_token, const float* __restrict__ row_gate,
    const int* __restrict__ ctrl, int cbase, ushort_t* __restrict__ Hout,
    float* __restrict__ out) {
  // 2048 blocks; 2048%8==0 -> simple bijective XCD swizzle (T1, m157)
  const int l = (blockIdx.x & 7) * 256 + (blockIdx.x >> 3);
  const int mt = l >> 3, nt = l & 7; // n fastest: 8 blocks share one A-panel
  const int Mpad = ctrl[C_MPAD];
  const int m0 = cbase + mt * 128;
  if (m0 >= Mpad) return;
  const int m0loc = m0 - cbase;
  const int n0 = nt * 128;
  int e = 0;
#pragma unroll
  for (int i = 0; i < NE - 1; i++)
    if (m0 >= ctrl[C_SEG(i + 1)]) e = i + 1;
  const ushort_t* B = Wt + ((size_t)e << 20);

  __shared__ ushort_t As[128 * 32];
  __shared__ ushort_t Bs[128 * 32];
  const int tid = threadIdx.x;
  const int lane = tid & 63;
  const int wave = tid >> 6;
  const int wm = wave >> 1, wn = wave & 1;
  const int lr = lane & 15;
  const int lk = (lane >> 4) << 3;

  const ushort_t* asrc0;
  const ushort_t* asrc1;
  if (PASS == 0) {
    int tk0 = row_token[m0 + (tid >> 2)];
    int tk1 = row_token[m0 + 64 + (tid >> 2)];
    if (tk0 >= TOK) tk0 = 0;
    if (tk1 >= TOK) tk1 = 0;
    asrc0 = Asrc + (size_t)tk0 * DIM + ((tid & 3) << 3);
    asrc1 = Asrc + (size_t)tk1 * DIM + ((tid & 3) << 3);
  } else {
    asrc0 = Asrc + (size_t)(m0loc + (tid >> 2)) * DIM + ((tid & 3) << 3);
    asrc1 = Asrc + (size_t)(m0loc + 64 + (tid >> 2)) * DIM + ((tid & 3) << 3);
  }
  const ushort_t* bsrc0 = B + (size_t)(n0 + (tid >> 2)) * DIM + ((tid & 3) << 3);
  const ushort_t* bsrc1 =
      B + (size_t)(n0 + 64 + (tid >> 2)) * DIM + ((tid & 3) << 3);
  ushort_t* lA0 = &As[(tid & ~63) * 8];
  ushort_t* lA1 = &As[(256 + (tid & ~63)) * 8];
  ushort_t* lB0 = &Bs[(tid & ~63) * 8];
  ushort_t* lB1 = &Bs[(256 + (tid & ~63)) * 8];

  f32x4 acc[4][4] = {};

  for (int k0 = 0; k0 < DIM; k0 += 32) {
    async16(lA0, asrc0 + k0);
    async16(lA1, asrc1 + k0);
    async16(lB0, bsrc0 + k0);
    async16(lB1, bsrc1 + k0);
    __syncthreads();
    bf16x8 a[4], b[4];
#pragma unroll
    for (int i = 0; i < 4; i++)
      a[i] = *(const bf16x8*)&As[(wm * 64 + i * 16 + lr) * 32 + lk];
#pragma unroll
    for (int i = 0; i < 4; i++)
      b[i] = *(const bf16x8*)&Bs[(wn * 64 + i * 16 + lr) * 32 + lk];
#pragma unroll
    for (int mi = 0; mi < 4; mi++)
#pragma unroll
      for (int ni = 0; ni < 4; ni++)
        acc[mi][ni] = __builtin_amdgcn_mfma_f32_16x16x32_bf16(
            a[mi], b[ni], acc[mi][ni], 0, 0, 0);
    __syncthreads();
  }

  const int grow = (lane >> 4) << 2;
  if (PASS == 0) {
#pragma unroll
    for (int mi = 0; mi < 4; mi++) {
      const int rloc = m0loc + wm * 64 + mi * 16 + grow;
#pragma unroll
      for (int ni = 0; ni < 4; ni++) {
        const int col = n0 + wn * 64 + ni * 16 + lr;
#pragma unroll
        for (int r = 0; r < 4; r++) {
          const float x = acc[mi][ni][r];
          const float g = 0.5f * x * (1.f + erff(x * 0.70710678118654752f));
          Hout[(size_t)(rloc + r) * DIM + col] = f2b(g);
        }
      }
    }
  } else {
#pragma unroll
    for (int mi = 0; mi < 4; mi++) {
      const int rbase = m0 + wm * 64 + mi * 16 + grow;
#pragma unroll
      for (int r = 0; r < 4; r++) {
        const int rr = rbase + r;
        const int tok = row_token[rr];
        if (tok < TOK) {
          const float g = row_gate[rr];
          float* op = out + (size_t)tok * DIM + n0 + wn * 64 + lr;
#pragma unroll
          for (int ni = 0; ni < 4; ni++)
            atomicAdd(op + ni * 16, g * acc[mi][ni][r]);
        }
      }
    }
  }
}

extern "C" void kernel_launch(void* const* d_in, const int* in_sizes, int n_in,
                              void* d_out, int out_size, void* d_ws,
                              size_t ws_size, hipStream_t stream) {
  (void)in_sizes; (void)n_in; (void)ws_size;
  const float* tokens = (const float*)d_in[0];
  const float* rw = (const float*)d_in[1];
  const float* w1 = (const float*)d_in[2];
  const float* w2 = (const float*)d_in[3];
  float* out = (float*)d_out;

  char* ws = (char*)d_ws;
  size_t off = 0;
  auto alloc = [&](size_t b) {
    size_t o = off;
    off += (b + 255) & ~(size_t)255;
    return o;
  };
  int* ctrl = (int*)(ws + alloc(2048));
  int* topi = (int*)(ws + alloc((size_t)TOK * 2 * 4));
  float* topv = (float*)(ws + alloc((size_t)TOK * 2 * 4));
  int* row_token = (int*)(ws + alloc((size_t)BMCAP * 4));
  float* row_gate = (float*)(ws + alloc((size_t)BMCAP * 4));
  ushort_t* X16 = (ushort_t*)(ws + alloc((size_t)TOK * DIM * 2));
  ushort_t* w1T = (ushort_t*)(ws + alloc((size_t)NE * DIM * DIM * 2));
  ushort_t* w2T = (ushort_t*)(ws + alloc((size_t)NE * DIM * DIM * 2));
  ushort_t* H = (ushort_t*)(ws + alloc((size_t)CH * DIM * 2));

  hipMemsetAsync(ctrl, 0, 2048, stream);
  router_seq3<<<TOK / 32, 256, 0, stream>>>(tokens, rw, topi, topv);
  hist_kernel<<<TOK * 2 / 512, 256, 0, stream>>>(topi, ctrl);
  prefix_kernel<<<1, 64, 0, stream>>>(ctrl);
  init_rows<<<(BMCAP + 255) / 256, 256, 0, stream>>>(row_token, row_gate);
  assign2<<<TOK / 256, 256, 0, stream>>>(topi, topv, ctrl, row_token,
                                         row_gate);
  cast_tokens<<<TOK * DIM / 8 / 256, 256, 0, stream>>>(tokens, X16);
  dim3 tg(16, 16, 8);
  transpose_cast<<<tg, 256, 0, stream>>>(w1, w1T);
  transpose_cast<<<tg, 256, 0, stream>>>(w2, w2T);
  hipMemsetAsync(out, 0, (size_t)out_size * 4, stream);
  for (int c = 0; c < NCHUNK; c++) {
    dgemm<0><<<2048, 256, 0, stream>>>(X16, w1T, row_token, row_gate, ctrl,
                                       c * CH, H, out);
    dgemm<1><<<2048, 256, 0, stream>>>(H, w2T, row_token, row_gate, ctrl,
                                       c * CH, H, out);
  }
}